// Round 5
// baseline (512.436 us; speedup 1.0000x reference)
//
#include <hip/hip_runtime.h>
#include <hip/hip_bf16.h>
#include <math.h>

// ---------------- workspace layout (float offsets) ----------------
#define WS_PB     0u         // P bf16  2048*256 ushort (rows 0..1023 = cos, 1024.. = -sin) = 262144 floats
#define WS_PYRE   262144u    // py_re  1024*256 fp32
#define WS_PYIM   524288u    // py_im  1024*256 fp32
#define WS_XB     786432u    // x bf16 16*65536 ushort = 524288 floats
#define WS_FEAT   1310720u   // feat   16*2048
#define WS_H1ACC  1343488u   // h1_acc 16*512
#define WS_H1F    1351680u   // h1f    16*512
#define WS_H2ACC  1359872u   // h2_acc 16*1024
#define WS_H2T    1376256u   // h2t    1024*16 (transposed, relu'd)
// total 1392640 floats = 5.6 MB

// d_out layout: x_hat [0,1048576) | y (16384 floats, real-only, complex->float32 cast)
//               | k_points (2048) ; y offset fixed, kp offset = out_size - 2048.
#define OUT_Y  1048576

typedef __attribute__((ext_vector_type(8))) short short8;
typedef __attribute__((ext_vector_type(4))) float f32x4;

__device__ inline unsigned short f2bf(float f) {
  __hip_bfloat16 h = __float2bfloat16(f);
  return *reinterpret_cast<unsigned short*>(&h);
}

// ---------------- K0: x fp32 -> bf16 ----------------
__global__ void k0_cvt(const float* __restrict__ x, unsigned short* __restrict__ xb) {
  int i = (blockIdx.x * 256 + threadIdx.x) * 4;  // grid 1024 -> 1,048,576 elems
  float4 v = *(const float4*)(x + i);
  ushort4 o;
  o.x = f2bf(v.x); o.y = f2bf(v.y); o.z = f2bf(v.z); o.w = f2bf(v.w);
  *(ushort4*)(xb + i) = o;
}

// ---------------- K1: trig tables (P in bf16, py in fp32) ----------------
__global__ void k1_trig(const float* __restrict__ kp, unsigned short* __restrict__ Pb,
                        float* __restrict__ pyre, float* __restrict__ pyim) {
  int bid = blockIdx.x, tid = threadIdx.x;
  const float TWO_PI = 6.28318530717958647692f;
  if (bid < 1024) {
    int t = bid, w = tid;
    float kx = kp[2 * t];
    float xx = -0.5f + (float)w * (1.0f / 255.0f);
    float s, c;
    sincosf(TWO_PI * kx * xx, &s, &c);
    Pb[t * 256 + w]          = f2bf(c);
    Pb[(1024 + t) * 256 + w] = f2bf(-s);
  } else {
    int t = bid - 1024, h = tid;
    float ky = kp[2 * t + 1];
    float yy = -0.5f + (float)h * (1.0f / 255.0f);
    float s, c;
    sincosf(TWO_PI * ky * yy, &s, &c);
    pyre[t * 256 + h] = c;
    pyim[t * 256 + h] = -s;
  }
}

// ---------------- K23: fused Fourier sample (MFMA) + y-reduce ----------------
// Per block: b = blockIdx.y, t-tile of 32 (re rows t0..t0+31, im rows 1024+t0..).
// C[t,h] tiles computed with mfma_f32_16x16x32_bf16; epilogue reduces over h
// against py and writes y/feat only (a_st never materialized).
// 256 thr = 4 waves; wave w owns h-quadrant w*64..w*64+63.
// A-frag: lane l holds A[row=l&15][k=(l>>4)*8+j]; B-frag: B[k=(l>>4)*8+j][col=l&15];
// C/D: col=lane&15, row=(lane>>4)*4+reg  (verified layouts).
#define TPAD 40  // padded LDS row length in shorts (80 B, 16B-aligned rows)

__launch_bounds__(256)
__global__ void k23_fused(const unsigned short* __restrict__ Pb,
                          const unsigned short* __restrict__ xb,
                          const float* __restrict__ pyre, const float* __restrict__ pyim,
                          float* __restrict__ feat, float* __restrict__ out_y,
                          float* __restrict__ h1_acc, int ymode) {
  __shared__ unsigned short Alds[64 * TPAD];
  __shared__ unsigned short Xlds[256 * TPAD];
  __shared__ float red[32][4][4];  // [t_local][wave][srr,sii,sri,sir]
  int tid = threadIdx.x;
  int b  = blockIdx.y;
  int t0 = blockIdx.x * 32;
  int w = tid >> 6, l = tid & 63;
  int g = l >> 4, c = l & 15;
  const unsigned short* xbase = xb + (size_t)b * 65536;

  f32x4 acc[4][4] = {};  // [mf][hf]; mf 0,1 = re t-rows +0/+16; mf 2,3 = im

  for (int ks = 0; ks < 8; ++ks) {
    int k0 = ks * 32;
    __syncthreads();  // prior iteration's LDS reads complete
    {   // stage A: 64 rows x 32 k ; thread: row tid>>2, 16B segment tid&3
      int row = tid >> 2, seg = tid & 3;
      int trow = (row < 32) ? (t0 + row) : (1024 + t0 + row - 32);
      *(uint4*)(&Alds[row * TPAD + seg * 8]) =
          *(const uint4*)(Pb + (size_t)trow * 256 + k0 + seg * 8);
    }
    {   // stage X: 256 rows x 32 k ; thread tid stages row tid (64 B)
      const unsigned short* src = xbase + (size_t)tid * 256 + k0;
      unsigned short* dst = &Xlds[tid * TPAD];
      *(uint4*)(dst)      = *(const uint4*)(src);
      *(uint4*)(dst + 8)  = *(const uint4*)(src + 8);
      *(uint4*)(dst + 16) = *(const uint4*)(src + 16);
      *(uint4*)(dst + 24) = *(const uint4*)(src + 24);
    }
    __syncthreads();
    short8 afr[4], bfr[4];
    #pragma unroll
    for (int mf = 0; mf < 4; ++mf)
      afr[mf] = *reinterpret_cast<const short8*>(&Alds[(mf * 16 + c) * TPAD + g * 8]);
    #pragma unroll
    for (int hf = 0; hf < 4; ++hf)
      bfr[hf] = *reinterpret_cast<const short8*>(&Xlds[(w * 64 + hf * 16 + c) * TPAD + g * 8]);
    #pragma unroll
    for (int mf = 0; mf < 4; ++mf)
      #pragma unroll
      for (int hf = 0; hf < 4; ++hf)
        acc[mf][hf] = __builtin_amdgcn_mfma_f32_16x16x32_bf16(afr[mf], bfr[hf], acc[mf][hf], 0, 0, 0);
  }

  // epilogue: lane-local py-weighted partials over this wave's h-quadrant
  float srr[2][4] = {{0}}, sii[2][4] = {{0}}, sri[2][4] = {{0}}, sir[2][4] = {{0}};
  #pragma unroll
  for (int mh = 0; mh < 2; ++mh)
    #pragma unroll
    for (int r = 0; r < 4; ++r) {
      int t = t0 + mh * 16 + g * 4 + r;
      #pragma unroll
      for (int hf = 0; hf < 4; ++hf) {
        int h = w * 64 + hf * 16 + c;
        float cr = pyre[t * 256 + h], ci = pyim[t * 256 + h];
        float vre = acc[mh][hf][r], vim = acc[mh + 2][hf][r];
        srr[mh][r] += vre * cr; sri[mh][r] += vre * ci;
        sir[mh][r] += vim * cr; sii[mh][r] += vim * ci;
      }
    }
  // reduce across the 16 lanes (columns) of this lane-group
  #pragma unroll
  for (int mh = 0; mh < 2; ++mh)
    #pragma unroll
    for (int r = 0; r < 4; ++r) {
      float a0 = srr[mh][r], a1 = sii[mh][r], a2 = sri[mh][r], a3 = sir[mh][r];
      #pragma unroll
      for (int off = 1; off < 16; off <<= 1) {
        a0 += __shfl_xor(a0, off, 64);
        a1 += __shfl_xor(a1, off, 64);
        a2 += __shfl_xor(a2, off, 64);
        a3 += __shfl_xor(a3, off, 64);
      }
      if (c == 0) {
        int tloc = mh * 16 + g * 4 + r;
        red[tloc][w][0] = a0; red[tloc][w][1] = a1;
        red[tloc][w][2] = a2; red[tloc][w][3] = a3;
      }
    }
  __syncthreads();
  if (tid < 32) {
    int t = t0 + tid;
    float yre = 0.f, yim = 0.f;
    #pragma unroll
    for (int ww = 0; ww < 4; ++ww) {
      yre += red[tid][ww][0] - red[tid][ww][1];
      yim += red[tid][ww][2] + red[tid][ww][3];
    }
    feat[b * 2048 + t]        = yre;
    feat[b * 2048 + 1024 + t] = yim;
    if (ymode == 0) {
      out_y[b * 1024 + t] = yre;
    } else {
      out_y[(b * 1024 + t) * 2]     = yre;
      out_y[(b * 1024 + t) * 2 + 1] = yim;
    }
  }
  if (blockIdx.y == 0) h1_acc[blockIdx.x * 256 + tid] = 0.f;  // zero 8192 floats
}

// ---------------- K4: h1_acc += feat @ W1 (split-K atomics) ----------------
__global__ void k4_w1(const float* __restrict__ feat, const float* __restrict__ W1,
                      float* __restrict__ h1_acc) {
  int nt = blockIdx.x & 1, ks = blockIdx.x >> 1;
  int n = nt * 256 + threadIdx.x;
  int k0 = ks * 64;
  float acc[16];
  #pragma unroll
  for (int b = 0; b < 16; ++b) acc[b] = 0.f;
  for (int k = k0; k < k0 + 64; ++k) {
    float w = W1[k * 512 + n];
    #pragma unroll
    for (int b = 0; b < 16; ++b) acc[b] += feat[b * 2048 + k] * w;
  }
  #pragma unroll
  for (int b = 0; b < 16; ++b) atomicAdd(&h1_acc[b * 512 + n], acc[b]);
}

// ---------------- K4b: h1f = relu(h1_acc + b1); zero h2_acc ----------------
__global__ void k4b_fin(const float* __restrict__ h1_acc, const float* __restrict__ b1,
                        float* __restrict__ h1f, float* __restrict__ h2_acc) {
  int i = blockIdx.x * 256 + threadIdx.x;  // grid 96 -> 24576
  if (i < 8192) {
    int k = i & 511;
    h1f[i] = fmaxf(h1_acc[i] + b1[k], 0.f);
  }
  if (i < 16384) h2_acc[i] = 0.f;
}

// ---------------- K5: h2_acc += h1f @ W2 (split-K atomics) ----------------
__global__ void k5_w2(const float* __restrict__ h1f, const float* __restrict__ W2,
                      float* __restrict__ h2_acc) {
  int nt = blockIdx.x & 3, ks = blockIdx.x >> 2;
  int n = nt * 256 + threadIdx.x;
  int k0 = ks * 32;
  float acc[16];
  #pragma unroll
  for (int b = 0; b < 16; ++b) acc[b] = 0.f;
  for (int k = k0; k < k0 + 32; ++k) {
    float w = W2[k * 1024 + n];
    #pragma unroll
    for (int b = 0; b < 16; ++b) acc[b] += h1f[b * 512 + k] * w;
  }
  #pragma unroll
  for (int b = 0; b < 16; ++b) atomicAdd(&h2_acc[b * 1024 + n], acc[b]);
}

// ---------------- K5b: h2t[k][b] = relu(h2_acc[b][k]+b2[k]); copy k_points ----------------
__global__ void k5b_fin(const float* __restrict__ h2_acc, const float* __restrict__ b2,
                        const float* __restrict__ kp, float* __restrict__ h2t,
                        float* __restrict__ out_kp) {
  int i = blockIdx.x * 256 + threadIdx.x;  // grid 72 -> 18432
  if (i < 16384) {
    int k = i >> 4, b = i & 15;
    h2t[i] = fmaxf(h2_acc[b * 1024 + k] + b2[k], 0.f);
  } else {
    int j = i - 16384;  // < 2048
    out_kp[j] = kp[j];
  }
}

// ---------------- K6: out = h2 @ W3 + b3 (the 268 MB kernel) ----------------
__launch_bounds__(512, 1)
__global__ void k6_w3(const float* __restrict__ h2t, const float* __restrict__ W3,
                      const float* __restrict__ b3, float* __restrict__ out) {
  __shared__ float red[256][17];
  int tn = threadIdx.x & 255;
  int kh = threadIdx.x >> 8;  // 0 or 1
  int n = blockIdx.x * 256 + tn;
  int k0 = kh * 512;
  float acc[16];
  #pragma unroll
  for (int b = 0; b < 16; ++b) acc[b] = 0.f;
  const float* w3p = W3 + (size_t)k0 * 65536 + n;
  const float4* hp = (const float4*)(h2t + k0 * 16);
  #pragma unroll 8
  for (int k = 0; k < 512; ++k) {
    float w = w3p[(size_t)k * 65536];
    float4 h0 = hp[k * 4 + 0];
    float4 h1 = hp[k * 4 + 1];
    float4 h2 = hp[k * 4 + 2];
    float4 h3 = hp[k * 4 + 3];
    acc[0]  += h0.x * w; acc[1]  += h0.y * w; acc[2]  += h0.z * w; acc[3]  += h0.w * w;
    acc[4]  += h1.x * w; acc[5]  += h1.y * w; acc[6]  += h1.z * w; acc[7]  += h1.w * w;
    acc[8]  += h2.x * w; acc[9]  += h2.y * w; acc[10] += h2.z * w; acc[11] += h2.w * w;
    acc[12] += h3.x * w; acc[13] += h3.y * w; acc[14] += h3.z * w; acc[15] += h3.w * w;
  }
  if (kh) {
    #pragma unroll
    for (int b = 0; b < 16; ++b) red[tn][b] = acc[b];
  }
  __syncthreads();
  if (!kh) {
    float bv = b3[n];
    #pragma unroll
    for (int b = 0; b < 16; ++b)
      out[(size_t)b * 65536 + n] = acc[b] + red[tn][b] + bv;
  }
}

// ---------------- launch ----------------
extern "C" void kernel_launch(void* const* d_in, const int* in_sizes, int n_in,
                              void* d_out, int out_size, void* d_ws, size_t ws_size,
                              hipStream_t stream) {
  const float* x  = (const float*)d_in[0];
  const float* kp = (const float*)d_in[1];
  const float* W1 = (const float*)d_in[2];
  const float* b1 = (const float*)d_in[3];
  const float* W2 = (const float*)d_in[4];
  const float* b2 = (const float*)d_in[5];
  const float* W3 = (const float*)d_in[6];
  const float* b3 = (const float*)d_in[7];
  float* out = (float*)d_out;
  float* ws  = (float*)d_ws;

  unsigned short* Pb = (unsigned short*)(ws + WS_PB);
  float* pyre   = ws + WS_PYRE;
  float* pyim   = ws + WS_PYIM;
  unsigned short* xb = (unsigned short*)(ws + WS_XB);
  float* feat   = ws + WS_FEAT;
  float* h1_acc = ws + WS_H1ACC;
  float* h1f    = ws + WS_H1F;
  float* h2_acc = ws + WS_H2ACC;
  float* h2t    = ws + WS_H2T;

  // y chunk flat size equals prod(y.shape)=16384 (complex cast to float32 ->
  // real part) when out_size == 1067008; otherwise assume interleaved pairs.
  int ymode = (out_size == 1048576 + 16384 + 2048) ? 0 : 1;
  float* out_y  = out + OUT_Y;
  float* out_kp = out + (out_size - 2048);

  k0_cvt<<<dim3(1024), dim3(256), 0, stream>>>(x, xb);
  k1_trig<<<dim3(2048), dim3(256), 0, stream>>>(kp, Pb, pyre, pyim);
  k23_fused<<<dim3(32, 16), dim3(256), 0, stream>>>(Pb, xb, pyre, pyim, feat, out_y, h1_acc, ymode);
  k4_w1<<<dim3(64), dim3(256), 0, stream>>>(feat, W1, h1_acc);
  k4b_fin<<<dim3(96), dim3(256), 0, stream>>>(h1_acc, b1, h1f, h2_acc);
  k5_w2<<<dim3(64), dim3(256), 0, stream>>>(h1f, W2, h2_acc);
  k5b_fin<<<dim3(72), dim3(256), 0, stream>>>(h2_acc, b2, kp, h2t, out_kp);
  k6_w3<<<dim3(256), dim3(512), 0, stream>>>(h2t, W3, b3, out);
}

// Round 6
// 439.645 us; speedup vs baseline: 1.1656x; 1.1656x over previous
//
#include <hip/hip_runtime.h>
#include <hip/hip_bf16.h>
#include <math.h>

// ---------------- workspace layout (float offsets) ----------------
#define WS_PB     0u         // P bf16  2048*256 ushort = 262144 float-slots
#define WS_PYRE   262144u    // py_re  1024*256 fp32
#define WS_PYIM   524288u    // py_im  1024*256 fp32
#define WS_XB     786432u    // x bf16 16*65536 ushort = 524288 float-slots
#define WS_FEAT   1310720u   // feat   16*2048
#define WS_H1ACC  1343488u   // h1_acc 16*512
#define WS_H1F    1351680u   // h1f    16*512
#define WS_H2ACC  1359872u   // h2_acc 16*1024
#define WS_H2T    1376256u   // h2t    1024*16 (transposed, relu'd)
#define WS_PT     1392640u   // pt     4*16*65536 split-K partials (16.8 MB)
// total 5586944 floats = 22.3 MB

// d_out layout: x_hat [0,1048576) | y (16384 floats, real-only) | k_points (2048)
#define OUT_Y  1048576

typedef __attribute__((ext_vector_type(8))) short short8;
typedef __attribute__((ext_vector_type(4))) float f32x4;

__device__ inline unsigned short f2bf(float f) {
  __hip_bfloat16 h = __float2bfloat16(f);
  return *reinterpret_cast<unsigned short*>(&h);
}

// ---------------- K0: x fp32 -> bf16 ----------------
__global__ void k0_cvt(const float* __restrict__ x, unsigned short* __restrict__ xb) {
  int i = (blockIdx.x * 256 + threadIdx.x) * 4;  // grid 1024 -> 1,048,576 elems
  float4 v = *(const float4*)(x + i);
  ushort4 o;
  o.x = f2bf(v.x); o.y = f2bf(v.y); o.z = f2bf(v.z); o.w = f2bf(v.w);
  *(ushort4*)(xb + i) = o;
}

// ---------------- K1: trig tables (P in bf16, py in fp32) ----------------
__global__ void k1_trig(const float* __restrict__ kp, unsigned short* __restrict__ Pb,
                        float* __restrict__ pyre, float* __restrict__ pyim) {
  int bid = blockIdx.x, tid = threadIdx.x;
  const float TWO_PI = 6.28318530717958647692f;
  if (bid < 1024) {
    int t = bid, w = tid;
    float kx = kp[2 * t];
    float xx = -0.5f + (float)w * (1.0f / 255.0f);
    float s, c;
    sincosf(TWO_PI * kx * xx, &s, &c);
    Pb[t * 256 + w]          = f2bf(c);
    Pb[(1024 + t) * 256 + w] = f2bf(-s);
  } else {
    int t = bid - 1024, h = tid;
    float ky = kp[2 * t + 1];
    float yy = -0.5f + (float)h * (1.0f / 255.0f);
    float s, c;
    sincosf(TWO_PI * ky * yy, &s, &c);
    pyre[t * 256 + h] = c;
    pyim[t * 256 + h] = -s;
  }
}

// ---------------- K23: fused Fourier sample (MFMA) + y-reduce ----------------
#define TPAD 40  // padded LDS row length in shorts (80 B, 16B-aligned rows)

__launch_bounds__(256)
__global__ void k23_fused(const unsigned short* __restrict__ Pb,
                          const unsigned short* __restrict__ xb,
                          const float* __restrict__ pyre, const float* __restrict__ pyim,
                          float* __restrict__ feat, float* __restrict__ out_y,
                          float* __restrict__ h1_acc, int ymode) {
  __shared__ unsigned short Alds[64 * TPAD];
  __shared__ unsigned short Xlds[256 * TPAD];
  __shared__ float red[32][4][4];  // [t_local][wave][srr,sii,sri,sir]
  int tid = threadIdx.x;
  int b  = blockIdx.y;
  int t0 = blockIdx.x * 32;
  int w = tid >> 6, l = tid & 63;
  int g = l >> 4, c = l & 15;
  const unsigned short* xbase = xb + (size_t)b * 65536;

  f32x4 acc[4][4] = {};  // [mf][hf]; mf 0,1 = re t-rows +0/+16; mf 2,3 = im

  for (int ks = 0; ks < 8; ++ks) {
    int k0 = ks * 32;
    __syncthreads();  // prior iteration's LDS reads complete
    {   // stage A: 64 rows x 32 k
      int row = tid >> 2, seg = tid & 3;
      int trow = (row < 32) ? (t0 + row) : (1024 + t0 + row - 32);
      *(uint4*)(&Alds[row * TPAD + seg * 8]) =
          *(const uint4*)(Pb + (size_t)trow * 256 + k0 + seg * 8);
    }
    {   // stage X: 256 rows x 32 k
      const unsigned short* src = xbase + (size_t)tid * 256 + k0;
      unsigned short* dst = &Xlds[tid * TPAD];
      *(uint4*)(dst)      = *(const uint4*)(src);
      *(uint4*)(dst + 8)  = *(const uint4*)(src + 8);
      *(uint4*)(dst + 16) = *(const uint4*)(src + 16);
      *(uint4*)(dst + 24) = *(const uint4*)(src + 24);
    }
    __syncthreads();
    short8 afr[4], bfr[4];
    #pragma unroll
    for (int mf = 0; mf < 4; ++mf)
      afr[mf] = *reinterpret_cast<const short8*>(&Alds[(mf * 16 + c) * TPAD + g * 8]);
    #pragma unroll
    for (int hf = 0; hf < 4; ++hf)
      bfr[hf] = *reinterpret_cast<const short8*>(&Xlds[(w * 64 + hf * 16 + c) * TPAD + g * 8]);
    #pragma unroll
    for (int mf = 0; mf < 4; ++mf)
      #pragma unroll
      for (int hf = 0; hf < 4; ++hf)
        acc[mf][hf] = __builtin_amdgcn_mfma_f32_16x16x32_bf16(afr[mf], bfr[hf], acc[mf][hf], 0, 0, 0);
  }

  // epilogue: lane-local py-weighted partials over this wave's h-quadrant
  float srr[2][4] = {{0}}, sii[2][4] = {{0}}, sri[2][4] = {{0}}, sir[2][4] = {{0}};
  #pragma unroll
  for (int mh = 0; mh < 2; ++mh)
    #pragma unroll
    for (int r = 0; r < 4; ++r) {
      int t = t0 + mh * 16 + g * 4 + r;
      #pragma unroll
      for (int hf = 0; hf < 4; ++hf) {
        int h = w * 64 + hf * 16 + c;
        float cr = pyre[t * 256 + h], ci = pyim[t * 256 + h];
        float vre = acc[mh][hf][r], vim = acc[mh + 2][hf][r];
        srr[mh][r] += vre * cr; sri[mh][r] += vre * ci;
        sir[mh][r] += vim * cr; sii[mh][r] += vim * ci;
      }
    }
  #pragma unroll
  for (int mh = 0; mh < 2; ++mh)
    #pragma unroll
    for (int r = 0; r < 4; ++r) {
      float a0 = srr[mh][r], a1 = sii[mh][r], a2 = sri[mh][r], a3 = sir[mh][r];
      #pragma unroll
      for (int off = 1; off < 16; off <<= 1) {
        a0 += __shfl_xor(a0, off, 64);
        a1 += __shfl_xor(a1, off, 64);
        a2 += __shfl_xor(a2, off, 64);
        a3 += __shfl_xor(a3, off, 64);
      }
      if (c == 0) {
        int tloc = mh * 16 + g * 4 + r;
        red[tloc][w][0] = a0; red[tloc][w][1] = a1;
        red[tloc][w][2] = a2; red[tloc][w][3] = a3;
      }
    }
  __syncthreads();
  if (tid < 32) {
    int t = t0 + tid;
    float yre = 0.f, yim = 0.f;
    #pragma unroll
    for (int ww = 0; ww < 4; ++ww) {
      yre += red[tid][ww][0] - red[tid][ww][1];
      yim += red[tid][ww][2] + red[tid][ww][3];
    }
    feat[b * 2048 + t]        = yre;
    feat[b * 2048 + 1024 + t] = yim;
    if (ymode == 0) {
      out_y[b * 1024 + t] = yre;
    } else {
      out_y[(b * 1024 + t) * 2]     = yre;
      out_y[(b * 1024 + t) * 2 + 1] = yim;
    }
  }
  if (blockIdx.y == 0) h1_acc[blockIdx.x * 256 + tid] = 0.f;  // zero 8192 floats
}

// ---------------- K4: h1_acc += feat @ W1 (split-K atomics) ----------------
__global__ void k4_w1(const float* __restrict__ feat, const float* __restrict__ W1,
                      float* __restrict__ h1_acc) {
  int nt = blockIdx.x & 1, ks = blockIdx.x >> 1;
  int n = nt * 256 + threadIdx.x;
  int k0 = ks * 64;
  float acc[16];
  #pragma unroll
  for (int b = 0; b < 16; ++b) acc[b] = 0.f;
  for (int k = k0; k < k0 + 64; ++k) {
    float w = W1[k * 512 + n];
    #pragma unroll
    for (int b = 0; b < 16; ++b) acc[b] += feat[b * 2048 + k] * w;
  }
  #pragma unroll
  for (int b = 0; b < 16; ++b) atomicAdd(&h1_acc[b * 512 + n], acc[b]);
}

// ---------------- K4b: h1f = relu(h1_acc + b1); zero h2_acc ----------------
__global__ void k4b_fin(const float* __restrict__ h1_acc, const float* __restrict__ b1,
                        float* __restrict__ h1f, float* __restrict__ h2_acc) {
  int i = blockIdx.x * 256 + threadIdx.x;  // grid 96 -> 24576
  if (i < 8192) {
    int k = i & 511;
    h1f[i] = fmaxf(h1_acc[i] + b1[k], 0.f);
  }
  if (i < 16384) h2_acc[i] = 0.f;
}

// ---------------- K5: h2_acc += h1f @ W2 (split-K atomics) ----------------
__global__ void k5_w2(const float* __restrict__ h1f, const float* __restrict__ W2,
                      float* __restrict__ h2_acc) {
  int nt = blockIdx.x & 3, ks = blockIdx.x >> 2;
  int n = nt * 256 + threadIdx.x;
  int k0 = ks * 32;
  float acc[16];
  #pragma unroll
  for (int b = 0; b < 16; ++b) acc[b] = 0.f;
  for (int k = k0; k < k0 + 32; ++k) {
    float w = W2[k * 1024 + n];
    #pragma unroll
    for (int b = 0; b < 16; ++b) acc[b] += h1f[b * 512 + k] * w;
  }
  #pragma unroll
  for (int b = 0; b < 16; ++b) atomicAdd(&h2_acc[b * 1024 + n], acc[b]);
}

// ---------------- K5b: h2t[k][b] = relu(h2_acc[b][k]+b2[k]); copy k_points ----------------
__global__ void k5b_fin(const float* __restrict__ h2_acc, const float* __restrict__ b2,
                        const float* __restrict__ kp, float* __restrict__ h2t,
                        float* __restrict__ out_kp) {
  int i = blockIdx.x * 256 + threadIdx.x;  // grid 72 -> 18432
  if (i < 16384) {
    int k = i >> 4, b = i & 15;
    h2t[i] = fmaxf(h2_acc[b * 1024 + k] + b2[k], 0.f);
  } else {
    int j = i - 16384;  // < 2048
    out_kp[j] = kp[j];
  }
}

// ---------------- K6: pt[kc][b][n] = sum_{k in chunk} h2[b][k]*W3[k][n] ----------------
// grid (128 n-blocks, 4 k-chunks) x 256 thr = 512 blocks (2/CU, 8 waves/CU).
// h2 chunk (256 k x 16 b = 16 KB) staged in LDS; broadcast reads. Each thread:
// 2 n-columns x 16 b accumulators; W3 streamed via coalesced float2 loads.
__launch_bounds__(256, 2)
__global__ void k6_w3(const float* __restrict__ h2t, const float* __restrict__ W3,
                      float* __restrict__ pt) {
  __shared__ float hs[256][16];
  int tid = threadIdx.x;
  int kc = blockIdx.y;
  int k0 = kc * 256;
  int n = blockIdx.x * 512 + tid * 2;
  {  // stage h2 chunk: thread tid loads k-row k0+tid (16 floats = 64 B)
    const float4* src = (const float4*)(h2t + (size_t)(k0 + tid) * 16);
    float4* dst = (float4*)hs[tid];
    dst[0] = src[0]; dst[1] = src[1]; dst[2] = src[2]; dst[3] = src[3];
  }
  __syncthreads();
  float accx[16] = {}, accy[16] = {};
  const float* w3p = W3 + (size_t)k0 * 65536 + n;
  #pragma unroll 8
  for (int k = 0; k < 256; ++k) {
    float2 w = *(const float2*)(w3p + (size_t)k * 65536);
    const float* hr = hs[k];
    #pragma unroll
    for (int b = 0; b < 16; ++b) {
      accx[b] += hr[b] * w.x;
      accy[b] += hr[b] * w.y;
    }
  }
  float* pb = pt + (size_t)kc * 16 * 65536 + n;
  #pragma unroll
  for (int b = 0; b < 16; ++b)
    *(float2*)(pb + (size_t)b * 65536) = make_float2(accx[b], accy[b]);
}

// ---------------- K6b: out[b][n] = sum_kc pt[kc][b][n] + b3[n] ----------------
__global__ void k6b_red(const float* __restrict__ pt, const float* __restrict__ b3,
                        float* __restrict__ out) {
  int i = (blockIdx.x * 256 + threadIdx.x) * 4;  // grid 1024 -> 1,048,576
  int n = i & 65535;
  float4 s = *(const float4*)(b3 + n);
  #pragma unroll
  for (int kc = 0; kc < 4; ++kc) {
    float4 p = *(const float4*)(pt + (size_t)kc * 1048576 + i);
    s.x += p.x; s.y += p.y; s.z += p.z; s.w += p.w;
  }
  *(float4*)(out + i) = s;
}

// ---------------- launch ----------------
extern "C" void kernel_launch(void* const* d_in, const int* in_sizes, int n_in,
                              void* d_out, int out_size, void* d_ws, size_t ws_size,
                              hipStream_t stream) {
  const float* x  = (const float*)d_in[0];
  const float* kp = (const float*)d_in[1];
  const float* W1 = (const float*)d_in[2];
  const float* b1 = (const float*)d_in[3];
  const float* W2 = (const float*)d_in[4];
  const float* b2 = (const float*)d_in[5];
  const float* W3 = (const float*)d_in[6];
  const float* b3 = (const float*)d_in[7];
  float* out = (float*)d_out;
  float* ws  = (float*)d_ws;

  unsigned short* Pb = (unsigned short*)(ws + WS_PB);
  float* pyre   = ws + WS_PYRE;
  float* pyim   = ws + WS_PYIM;
  unsigned short* xb = (unsigned short*)(ws + WS_XB);
  float* feat   = ws + WS_FEAT;
  float* h1_acc = ws + WS_H1ACC;
  float* h1f    = ws + WS_H1F;
  float* h2_acc = ws + WS_H2ACC;
  float* h2t    = ws + WS_H2T;
  float* pt     = ws + WS_PT;

  int ymode = (out_size == 1048576 + 16384 + 2048) ? 0 : 1;
  float* out_y  = out + OUT_Y;
  float* out_kp = out + (out_size - 2048);

  k0_cvt<<<dim3(1024), dim3(256), 0, stream>>>(x, xb);
  k1_trig<<<dim3(2048), dim3(256), 0, stream>>>(kp, Pb, pyre, pyim);
  k23_fused<<<dim3(32, 16), dim3(256), 0, stream>>>(Pb, xb, pyre, pyim, feat, out_y, h1_acc, ymode);
  k4_w1<<<dim3(64), dim3(256), 0, stream>>>(feat, W1, h1_acc);
  k4b_fin<<<dim3(96), dim3(256), 0, stream>>>(h1_acc, b1, h1f, h2_acc);
  k5_w2<<<dim3(64), dim3(256), 0, stream>>>(h1f, W2, h2_acc);
  k5b_fin<<<dim3(72), dim3(256), 0, stream>>>(h2_acc, b2, kp, h2t, out_kp);
  k6_w3<<<dim3(128, 4), dim3(256), 0, stream>>>(h2t, W3, pt);
  k6b_red<<<dim3(1024), dim3(256), 0, stream>>>(pt, b3, out);
}